// Round 11
// baseline (216.859 us; speedup 1.0000x reference)
//
#include <hip/hip_runtime.h>

#define BB 32
#define NN 1024
#define FF 7
#define HID 256
#define MLPH 64
#define OUTN 8
#define CATN (MLPH + HID + 8)   // 328

__device__ __forceinline__ float wave_sum(float v) {
#pragma unroll
    for (int m = 32; m >= 1; m >>= 1) v += __shfl_xor(v, m, 64);
    return v;
}
__device__ __forceinline__ float wave_max(float v) {
#pragma unroll
    for (int m = 32; m >= 1; m >>= 1) v = fmaxf(v, __shfl_xor(v, m, 64));
    return v;
}

// ================= D1: pass1 + MLP-L1 + E-collapse + spd + cnt=0 =================
// blocks [0,256):   pass1 unit (b = blk>>3, jg = blk&7): 128 j x 1024 k, 2 j/thread.
//                   writes deg, bmaxp; jg==0 also spd[b] and cnt[b]=0.
// blocks [256,320): MLP-L1, one block per h: Wm0 row in LDS, loop 32 batches.
// blocks [320,328): weight collapse E = (Wp_gcn@Wfc)@W2, cE.
__global__ __launch_bounds__(1024, 2) void kD1(const float* __restrict__ x,
                                               const float* __restrict__ Wm0,
                                               const float* __restrict__ W2,
                                               const float* __restrict__ b2,
                                               const float* __restrict__ Wfc,
                                               const float* __restrict__ bfc,
                                               const float* __restrict__ Wp,
                                               float* __restrict__ deg,
                                               float* __restrict__ bmaxp,
                                               float* __restrict__ spd,
                                               float* __restrict__ mlp_p,
                                               float* __restrict__ E,
                                               float* __restrict__ cE,
                                               unsigned* __restrict__ cnt) {
    __shared__ __align__(16) float sbuf[NN * FF];   // 28 KB, aliased per role
    __shared__ float wred[16];
    int blk = blockIdx.x, tid = threadIdx.x, lane = tid & 63, w = tid >> 6;
    if (blk < 256) {
        float* l0 = sbuf;
        float* l1 = sbuf + NN;
        float* s2 = sbuf + 2 * NN;
        float* s3 = sbuf + 3 * NN;
        int b = blk >> 3, jg = blk & 7;
        const float* xb = x + b * (NN * FF);
        l0[tid] = xb[tid * FF + 1];
        l1[tid] = xb[tid * FF + 2];
        __syncthreads();
        int jA = jg * 128 + lane, jB = jA + 64;
        float pj0a = l0[jA], pj1a = l1[jA];
        float pj0b = l0[jB], pj1b = l1[jB];
        const float4* v0p = (const float4*)&l0[w * 64];
        const float4* v1p = (const float4*)&l1[w * 64];
        unsigned dA = 0u, dB = 0u;
        float mx = 0.f;
#pragma unroll 4
        for (int g = 0; g < 16; ++g) {
            float4 v0 = v0p[g], v1 = v1p[g];
            float dx, dy, d2a, d2b;
            dx = pj0a - v0.x; dy = pj1a - v1.x; d2a = fmaf(dy, dy, dx * dx);
            dx = pj0b - v0.x; dy = pj1b - v1.x; d2b = fmaf(dy, dy, dx * dx);
            dA += (d2a <= 0.09f); dB += (d2b <= 0.09f);
            mx = fmaxf(mx, fmaxf(d2a, d2b));
            dx = pj0a - v0.y; dy = pj1a - v1.y; d2a = fmaf(dy, dy, dx * dx);
            dx = pj0b - v0.y; dy = pj1b - v1.y; d2b = fmaf(dy, dy, dx * dx);
            dA += (d2a <= 0.09f); dB += (d2b <= 0.09f);
            mx = fmaxf(mx, fmaxf(d2a, d2b));
            dx = pj0a - v0.z; dy = pj1a - v1.z; d2a = fmaf(dy, dy, dx * dx);
            dx = pj0b - v0.z; dy = pj1b - v1.z; d2b = fmaf(dy, dy, dx * dx);
            dA += (d2a <= 0.09f); dB += (d2b <= 0.09f);
            mx = fmaxf(mx, fmaxf(d2a, d2b));
            dx = pj0a - v0.w; dy = pj1a - v1.w; d2a = fmaf(dy, dy, dx * dx);
            dx = pj0b - v0.w; dy = pj1b - v1.w; d2b = fmaf(dy, dy, dx * dx);
            dA += (d2a <= 0.09f); dB += (d2b <= 0.09f);
            mx = fmaxf(mx, fmaxf(d2a, d2b));
        }
        s2[tid] = (float)dA;
        s3[tid] = (float)dB;
        mx = wave_max(mx);
        if (lane == 0) wred[w] = mx;
        __syncthreads();
        if (tid < 64) {
            float s = 0.f;
#pragma unroll
            for (int kk = 0; kk < 16; ++kk) s += s2[kk * 64 + tid];
            deg[b * NN + jg * 128 + tid] = s;
        } else if (tid < 128) {
            int t = tid - 64;
            float s = 0.f;
#pragma unroll
            for (int kk = 0; kk < 16; ++kk) s += s3[kk * 64 + t];
            deg[b * NN + jg * 128 + 64 + t] = s;
        }
        if (tid == 0) {
            float m = wred[0];
#pragma unroll
            for (int i = 1; i < 16; ++i) m = fmaxf(m, wred[i]);
            bmaxp[b * 8 + jg] = m;
        }
        if (jg == 0) {
            float vx = xb[tid * FF + 3], vy = xb[tid * FF + 4];
            float sp = sqrtf(fmaf(vx, vx, vy * vy));
            sp = wave_sum(sp);
            __syncthreads();
            if (lane == 0) wred[w] = sp;
            __syncthreads();
            if (tid == 0) {
                float s = 0.f;
#pragma unroll
                for (int i = 0; i < 16; ++i) s += wred[i];
                spd[b] = s;
                cnt[b] = 0u;   // reset per-batch arrival counter for D2
            }
        }
    } else if (blk < 320) {
        int h = blk - 256;
        const float4* wr = (const float4*)(Wm0 + h * (NN * FF));
        float4* s4 = (float4*)sbuf;
        for (int i = tid; i < 1792; i += 1024) s4[i] = wr[i];   // Wm0 row once
        __syncthreads();
#pragma unroll
        for (int rep = 0; rep < 2; ++rep) {
            int b = w * 2 + rep;
            const float4* xr = (const float4*)(x + b * (NN * FF));
            float4 a4 = {0.f, 0.f, 0.f, 0.f};
#pragma unroll 7
            for (int it = 0; it < 28; ++it) {
                float4 xv = xr[it * 64 + lane];
                float4 wv = s4[it * 64 + lane];
                a4.x = fmaf(wv.x, xv.x, a4.x);
                a4.y = fmaf(wv.y, xv.y, a4.y);
                a4.z = fmaf(wv.z, xv.z, a4.z);
                a4.w = fmaf(wv.w, xv.w, a4.w);
            }
            float s = (a4.x + a4.y) + (a4.z + a4.w);
            s = wave_sum(s);
            if (lane == 0) mlp_p[b * MLPH + h] = s;
        }
    } else {
        int o = blk - 320;
        float* l0 = sbuf;
        float* l1 = sbuf + 256;
        float* r2 = sbuf + 512;
        if (tid < HID) l0[tid] = Wp[o * CATN + MLPH + tid];
        __syncthreads();
        if (tid < HID) {
            float a = 0.f;
#pragma unroll 8
            for (int m = 0; m < HID; ++m) a = fmaf(l0[m], Wfc[m * HID + tid], a);
            l1[tid] = a;
            r2[tid] = l0[tid] * bfc[tid];
        }
        __syncthreads();
        if (tid < HID) {
            float e = 0.f;
#pragma unroll 8
            for (int k = 0; k < HID; ++k) e = fmaf(l1[k], W2[k * HID + tid], e);
            E[o * HID + tid] = e;
            float c = fmaf(l1[tid], b2[tid], r2[tid]);
            c = wave_sum(c);
            if (lane == 0) wred[w] = c;
        }
        __syncthreads();
        if (tid == 0) cE[o] = wred[0] + wred[1] + wred[2] + wred[3];
    }
}

// ================= D2: pass2 + hsum partial + side roles + last-block epilogue ===
// 256 blocks (b = blk>>3, jg = blk&7). Each computes q/w for its 128 j (in LDS),
// then its hsum partial hp[b*8+jg][256]. jg==1 also xf2, jg==2 also glo.
// Last arriving block of batch b (atomic cnt) computes out[b].
__global__ __launch_bounds__(1024, 2) void kD2(const float* __restrict__ x,
                                               const float* __restrict__ deg,
                                               const float* __restrict__ W1,
                                               const float* __restrict__ b1,
                                               const float* __restrict__ Wg,
                                               const float* __restrict__ bg,
                                               const float* __restrict__ Wm1,
                                               const float* __restrict__ bm1,
                                               const float* __restrict__ Wp,
                                               const float* __restrict__ bp,
                                               const float* __restrict__ bm0,
                                               const float* __restrict__ mlp_p,
                                               const float* __restrict__ bmaxp,
                                               const float* __restrict__ spd,
                                               const float* __restrict__ E,
                                               const float* __restrict__ cE,
                                               float* __restrict__ hp,
                                               float* __restrict__ xf2g,
                                               float* __restrict__ sglog,
                                               unsigned* __restrict__ cnt,
                                               float* __restrict__ out) {
    __shared__ __align__(16) float l0[NN];
    __shared__ __align__(16) float l1[NN];
    __shared__ __align__(16) float di[NN];
    __shared__ __align__(16) float r0a[NN];
    __shared__ __align__(16) float r1a[NN];
    __shared__ __align__(16) float r2a[NN];
    __shared__ __align__(16) float r0b[NN];
    __shared__ __align__(16) float r1b[NN];
    __shared__ __align__(16) float r2b[NN];
    __shared__ __align__(16) float sq0[128];
    __shared__ __align__(16) float sq1[128];
    __shared__ __align__(16) float swj[128];
    __shared__ __align__(16) float hpp[4][HID];
    __shared__ unsigned s_old;
    int blk = blockIdx.x, tid = threadIdx.x, lane = tid & 63, w = tid >> 6;
    int b = blk >> 3, jg = blk & 7;
    const float* xb = x + b * (NN * FF);
    l0[tid] = xb[tid * FF + 1];
    l1[tid] = xb[tid * FF + 2];
    di[tid] = 1.0f / sqrtf(deg[b * NN + tid]);
    __syncthreads();
    int jA = jg * 128 + lane, jB = jA + 64;
    float pj0a = l0[jA], pj1a = l1[jA];
    float pj0b = l0[jB], pj1b = l1[jB];
    const float4* v0p = (const float4*)&l0[w * 64];
    const float4* v1p = (const float4*)&l1[w * 64];
    const float4* vdp = (const float4*)&di[w * 64];
    float a0a = 0.f, a1a = 0.f, asa = 0.f;
    float a0b = 0.f, a1b = 0.f, asb = 0.f;
#pragma unroll 4
    for (int g = 0; g < 16; ++g) {
        float4 v0 = v0p[g], v1 = v1p[g], vd = vdp[g];
        float dx, dy, d2, t;
        dx = pj0a - v0.x; dy = pj1a - v1.x; d2 = fmaf(dy, dy, dx * dx);
        t = (d2 <= 0.09f) ? vd.x : 0.0f;
        a0a = fmaf(t, v0.x, a0a); a1a = fmaf(t, v1.x, a1a); asa += t;
        dx = pj0b - v0.x; dy = pj1b - v1.x; d2 = fmaf(dy, dy, dx * dx);
        t = (d2 <= 0.09f) ? vd.x : 0.0f;
        a0b = fmaf(t, v0.x, a0b); a1b = fmaf(t, v1.x, a1b); asb += t;
        dx = pj0a - v0.y; dy = pj1a - v1.y; d2 = fmaf(dy, dy, dx * dx);
        t = (d2 <= 0.09f) ? vd.y : 0.0f;
        a0a = fmaf(t, v0.y, a0a); a1a = fmaf(t, v1.y, a1a); asa += t;
        dx = pj0b - v0.y; dy = pj1b - v1.y; d2 = fmaf(dy, dy, dx * dx);
        t = (d2 <= 0.09f) ? vd.y : 0.0f;
        a0b = fmaf(t, v0.y, a0b); a1b = fmaf(t, v1.y, a1b); asb += t;
        dx = pj0a - v0.z; dy = pj1a - v1.z; d2 = fmaf(dy, dy, dx * dx);
        t = (d2 <= 0.09f) ? vd.z : 0.0f;
        a0a = fmaf(t, v0.z, a0a); a1a = fmaf(t, v1.z, a1a); asa += t;
        dx = pj0b - v0.z; dy = pj1b - v1.z; d2 = fmaf(dy, dy, dx * dx);
        t = (d2 <= 0.09f) ? vd.z : 0.0f;
        a0b = fmaf(t, v0.z, a0b); a1b = fmaf(t, v1.z, a1b); asb += t;
        dx = pj0a - v0.w; dy = pj1a - v1.w; d2 = fmaf(dy, dy, dx * dx);
        t = (d2 <= 0.09f) ? vd.w : 0.0f;
        a0a = fmaf(t, v0.w, a0a); a1a = fmaf(t, v1.w, a1a); asa += t;
        dx = pj0b - v0.w; dy = pj1b - v1.w; d2 = fmaf(dy, dy, dx * dx);
        t = (d2 <= 0.09f) ? vd.w : 0.0f;
        a0b = fmaf(t, v0.w, a0b); a1b = fmaf(t, v1.w, a1b); asb += t;
    }
    r0a[tid] = a0a; r1a[tid] = a1a; r2a[tid] = asa;
    r0b[tid] = a0b; r1b[tid] = a1b; r2b[tid] = asb;
    __syncthreads();
    if (tid < 128) {
        int t = tid & 63;
        const float* R0 = (tid < 64) ? r0a : r0b;
        const float* R1 = (tid < 64) ? r1a : r1b;
        const float* R2 = (tid < 64) ? r2a : r2b;
        int jl = ((tid < 64) ? 0 : 64) + t;   // local j within the 128-slice
        float s0 = 0.f, s1 = 0.f, ss = 0.f;
#pragma unroll
        for (int kk = 0; kk < 16; ++kk) {
            s0 += R0[kk * 64 + t];
            s1 += R1[kk * 64 + t];
            ss += R2[kk * 64 + t];
        }
        float dj = di[jg * 128 + jl];
        sq0[jl] = dj * s0;
        sq1[jl] = dj * s1;
        swj[jl] = dj * ss * (1.0f / NN);
    }
    __syncthreads();
    // hsum partial over this block's 128 j: h = tid&255, jq = tid>>8 (32 j each)
    {
        int h = tid & 255, jq = tid >> 8;
        float w10 = W1[h * 2], w11 = W1[h * 2 + 1], bb = b1[h];
        float acc = 0.f;
        const float* q0v = &sq0[jq * 32];
        const float* q1v = &sq1[jq * 32];
        const float* wv  = &swj[jq * 32];
#pragma unroll 8
        for (int i = 0; i < 32; ++i) {
            float t = fmaf(q1v[i], w11, fmaf(q0v[i], w10, bb));
            acc = fmaf(wv[i], fmaxf(t, 0.f), acc);
        }
        hpp[jq][h] = acc;
    }
    __syncthreads();
    if (tid < HID)
        hp[(b * 8 + jg) * HID + tid] =
            hpp[0][tid] + hpp[1][tid] + hpp[2][tid] + hpp[3][tid];
    // side roles
    if (jg == 1 && tid < MLPH) {   // xf2 for batch b
        // reuse r0a as sx1 scratch (free now)
        r0a[tid] = fmaxf(mlp_p[b * MLPH + tid] + bm0[tid], 0.f);
    }
    if (jg == 1) __syncthreads();
    if (jg == 1 && tid < MLPH) {
        float a = bm1[tid];
        const float* wv = Wm1 + tid * MLPH;
#pragma unroll
        for (int k = 0; k < MLPH; ++k) a = fmaf(wv[k], r0a[k], a);
        xf2g[b * MLPH + tid] = fmaxf(a, 0.f);
    }
    if (jg == 2 && tid < 8) {      // global branch for batch b
        float mx = 0.f;
#pragma unroll
        for (int g = 0; g < 8; ++g) mx = fmaxf(mx, bmaxp[b * 8 + g]);
        float avg  = spd[b] * (1.0f / NN);
        float dens = 1.0f / sqrtf(mx);
        sglog[b * 8 + tid] =
            fmaxf(fmaf(Wg[tid * 2], avg, fmaf(Wg[tid * 2 + 1], dens, bg[tid])), 0.f);
    }
    // arrival: last block of batch b runs the epilogue
    __syncthreads();
    __threadfence();
    if (tid == 0) s_old = atomicAdd(&cnt[b], 1u);
    __syncthreads();
    if (s_old == 7u) {
        __threadfence();
        // hs = sum of 8 hp slices (reuse r1a as hs)
        if (tid < HID) {
            float s = 0.f;
#pragma unroll
            for (int g = 0; g < 8; ++g) s += hp[(b * 8 + g) * HID + tid];
            r1a[tid] = s;
        }
        if (tid >= 512 && tid < 576) r2a[tid - 512] = xf2g[b * MLPH + (tid - 512)];
        if (tid >= 576 && tid < 584) r2b[tid - 576] = sglog[b * 8 + (tid - 576)];
        __syncthreads();
        if (tid < 512) {
            int o = tid >> 6;
            const float* Eo = E + o * HID;
            float a = Eo[lane] * r1a[lane];
            a = fmaf(Eo[lane + 64],  r1a[lane + 64],  a);
            a = fmaf(Eo[lane + 128], r1a[lane + 128], a);
            a = fmaf(Eo[lane + 192], r1a[lane + 192], a);
            a = fmaf(Wp[o * CATN + lane], r2a[lane], a);
            a = wave_sum(a);
            if (lane == 0) {
                const float* wg = Wp + o * CATN + MLPH + HID;
#pragma unroll
                for (int g = 0; g < 8; ++g) a = fmaf(wg[g], r2b[g], a);
                out[b * OUTN + o] = a + cE[o] + bp[o];
            }
        }
    }
}

extern "C" void kernel_launch(void* const* d_in, const int* in_sizes, int n_in,
                              void* d_out, int out_size, void* d_ws, size_t ws_size,
                              hipStream_t stream) {
    const float* x   = (const float*)d_in[0];
    const float* W1  = (const float*)d_in[1];
    const float* b1  = (const float*)d_in[2];
    const float* W2  = (const float*)d_in[3];
    const float* b2  = (const float*)d_in[4];
    const float* Wfc = (const float*)d_in[5];
    const float* bfc = (const float*)d_in[6];
    const float* Wg  = (const float*)d_in[7];
    const float* bg  = (const float*)d_in[8];
    const float* Wm0 = (const float*)d_in[9];
    const float* bm0 = (const float*)d_in[10];
    const float* Wm1 = (const float*)d_in[11];
    const float* bm1 = (const float*)d_in[12];
    const float* Wp  = (const float*)d_in[13];
    const float* bp  = (const float*)d_in[14];
    float* out = (float*)d_out;
    float* ws  = (float*)d_ws;

    float*    deg   = ws;              // 32768
    float*    mlp_p = ws + 32768;      // 2048
    float*    bmaxp = ws + 34816;      // 256
    float*    spd   = ws + 35072;      // 32
    float*    E     = ws + 35104;      // 2048
    float*    cE    = ws + 37152;      // 8
    float*    hp    = ws + 37160;      // 32*8*256 = 65536
    float*    xf2g  = ws + 102696;     // 2048
    float*    sglog = ws + 104744;     // 256
    unsigned* cnt   = (unsigned*)(ws + 105000); // 32
    // cnt is zeroed by kD1 (stream-ordered before kD2); all else written before read.

    kD1<<<328, 1024, 0, stream>>>(x, Wm0, W2, b2, Wfc, bfc, Wp,
                                  deg, bmaxp, spd, mlp_p, E, cE, cnt);
    kD2<<<256, 1024, 0, stream>>>(x, deg, W1, b1, Wg, bg, Wm1, bm1, Wp, bp,
                                  bm0, mlp_p, bmaxp, spd, E, cE,
                                  hp, xf2g, sglog, cnt, out);
}

// Round 12
// 128.904 us; speedup vs baseline: 1.6823x; 1.6823x over previous
//
#include <hip/hip_runtime.h>

#define BB 32
#define NN 1024
#define FF 7
#define HID 256
#define MLPH 64
#define OUTN 8
#define CATN (MLPH + HID + 8)   // 328

__device__ __forceinline__ float wave_sum(float v) {
#pragma unroll
    for (int m = 32; m >= 1; m >>= 1) v += __shfl_xor(v, m, 64);
    return v;
}
__device__ __forceinline__ float wave_max(float v) {
#pragma unroll
    for (int m = 32; m >= 1; m >>= 1) v = fmaxf(v, __shfl_xor(v, m, 64));
    return v;
}

// kPM: blocks [0,32): repack x -> pts SoA (coalesced, x read ONCE) + speed sum.
//      blocks [32,40): weight collapse E = (Wp_gcn@Wfc)@W2, cE.
//      blocks [40,104): MLP-L1 GEMV — one block per h, Wm0 row staged in LDS
//      (Wm0 read ONCE), loop over all 32 b (x rows served from L2).
__global__ __launch_bounds__(1024, 4) void kPM(const float* __restrict__ x,
                                               const float* __restrict__ Wm0,
                                               const float* __restrict__ W2,
                                               const float* __restrict__ b2,
                                               const float* __restrict__ Wfc,
                                               const float* __restrict__ bfc,
                                               const float* __restrict__ Wp,
                                               float* __restrict__ pts0,
                                               float* __restrict__ pts1,
                                               float* __restrict__ spd,
                                               float* __restrict__ mlp_p,
                                               float* __restrict__ E,
                                               float* __restrict__ cE) {
    __shared__ __align__(16) float sbuf[NN * FF];   // 28 KB
    __shared__ float wred[16];
    int blk = blockIdx.x, tid = threadIdx.x, lane = tid & 63, w = tid >> 6;
    if (blk < 32) {
        int b = blk;
        const float4* xr = (const float4*)(x + b * (NN * FF));
        float4* s4 = (float4*)sbuf;
        for (int i = tid; i < 1792; i += 1024) s4[i] = xr[i];   // coalesced stream
        __syncthreads();
        pts0[b * NN + tid] = sbuf[tid * FF + 1];   // LDS extract, global coalesced
        pts1[b * NN + tid] = sbuf[tid * FF + 2];
        float vx = sbuf[tid * FF + 3], vy = sbuf[tid * FF + 4];
        float sp = sqrtf(fmaf(vx, vx, vy * vy));
        sp = wave_sum(sp);
        if (lane == 0) wred[w] = sp;
        __syncthreads();
        if (tid == 0) {
            float s = 0.f;
#pragma unroll
            for (int i = 0; i < 16; ++i) s += wred[i];
            spd[b] = s;
        }
    } else if (blk < 40) {
        int o = blk - 32;
        float* l0 = sbuf;
        float* l1 = sbuf + 256;
        float* r2 = sbuf + 512;
        if (tid < HID) l0[tid] = Wp[o * CATN + MLPH + tid];
        __syncthreads();
        if (tid < HID) {
            float a = 0.f;
#pragma unroll 8
            for (int m = 0; m < HID; ++m) a = fmaf(l0[m], Wfc[m * HID + tid], a);
            l1[tid] = a;
            r2[tid] = l0[tid] * bfc[tid];
        }
        __syncthreads();
        if (tid < HID) {
            float e = 0.f;
#pragma unroll 8
            for (int k = 0; k < HID; ++k) e = fmaf(l1[k], W2[k * HID + tid], e);
            E[o * HID + tid] = e;
            float c = fmaf(l1[tid], b2[tid], r2[tid]);
            c = wave_sum(c);
            if (lane == 0) wred[w] = c;
        }
        __syncthreads();
        if (tid == 0) cE[o] = wred[0] + wred[1] + wred[2] + wred[3];
    } else {
        int h = blk - 40;
        const float4* wr = (const float4*)(Wm0 + h * (NN * FF));
        float4* s4 = (float4*)sbuf;
        for (int i = tid; i < 1792; i += 1024) s4[i] = wr[i];   // Wm0 row -> LDS once
        __syncthreads();
#pragma unroll
        for (int rep = 0; rep < 2; ++rep) {
            int b = w * 2 + rep;                 // each wave owns 2 batches
            const float4* xr = (const float4*)(x + b * (NN * FF));
            float4 a4 = {0.f, 0.f, 0.f, 0.f};
#pragma unroll 7
            for (int it = 0; it < 28; ++it) {
                float4 xv = xr[it * 64 + lane];
                float4 wv = s4[it * 64 + lane];
                a4.x = fmaf(wv.x, xv.x, a4.x);
                a4.y = fmaf(wv.y, xv.y, a4.y);
                a4.z = fmaf(wv.z, xv.z, a4.z);
                a4.w = fmaf(wv.w, xv.w, a4.w);
            }
            float s = (a4.x + a4.y) + (a4.z + a4.w);
            s = wave_sum(s);
            if (lane == 0) mlp_p[b * MLPH + h] = s;
        }
    }
}

// kA: pass1, 256 blocks (b = blk>>3, jg = blk&7), 128 j x 1024 k, 2 j/thread.
// Staging: 2 coalesced dword loads from compact pts SoA (8 KB/block).
__global__ __launch_bounds__(1024, 4) void kA(const float* __restrict__ pts0,
                                              const float* __restrict__ pts1,
                                              float* __restrict__ deg,
                                              float* __restrict__ bmaxp) {
    __shared__ __align__(16) float l0[NN];
    __shared__ __align__(16) float l1[NN];
    __shared__ __align__(16) float s2[NN];
    __shared__ __align__(16) float s3[NN];
    __shared__ float wred[16];
    int blk = blockIdx.x, tid = threadIdx.x, lane = tid & 63, w = tid >> 6;
    int b = blk >> 3, jg = blk & 7;
    l0[tid] = pts0[b * NN + tid];
    l1[tid] = pts1[b * NN + tid];
    __syncthreads();
    int jA = jg * 128 + lane, jB = jA + 64;
    float pj0a = l0[jA], pj1a = l1[jA];
    float pj0b = l0[jB], pj1b = l1[jB];
    const float4* v0p = (const float4*)&l0[w * 64];
    const float4* v1p = (const float4*)&l1[w * 64];
    unsigned dA = 0u, dB = 0u;
    float mx = 0.f;
#pragma unroll 4
    for (int g = 0; g < 16; ++g) {
        float4 v0 = v0p[g], v1 = v1p[g];
        float dx, dy, d2a, d2b;
        dx = pj0a - v0.x; dy = pj1a - v1.x; d2a = fmaf(dy, dy, dx * dx);
        dx = pj0b - v0.x; dy = pj1b - v1.x; d2b = fmaf(dy, dy, dx * dx);
        dA += (d2a <= 0.09f); dB += (d2b <= 0.09f);
        mx = fmaxf(mx, fmaxf(d2a, d2b));
        dx = pj0a - v0.y; dy = pj1a - v1.y; d2a = fmaf(dy, dy, dx * dx);
        dx = pj0b - v0.y; dy = pj1b - v1.y; d2b = fmaf(dy, dy, dx * dx);
        dA += (d2a <= 0.09f); dB += (d2b <= 0.09f);
        mx = fmaxf(mx, fmaxf(d2a, d2b));
        dx = pj0a - v0.z; dy = pj1a - v1.z; d2a = fmaf(dy, dy, dx * dx);
        dx = pj0b - v0.z; dy = pj1b - v1.z; d2b = fmaf(dy, dy, dx * dx);
        dA += (d2a <= 0.09f); dB += (d2b <= 0.09f);
        mx = fmaxf(mx, fmaxf(d2a, d2b));
        dx = pj0a - v0.w; dy = pj1a - v1.w; d2a = fmaf(dy, dy, dx * dx);
        dx = pj0b - v0.w; dy = pj1b - v1.w; d2b = fmaf(dy, dy, dx * dx);
        dA += (d2a <= 0.09f); dB += (d2b <= 0.09f);
        mx = fmaxf(mx, fmaxf(d2a, d2b));
    }
    s2[tid] = (float)dA;
    s3[tid] = (float)dB;
    mx = wave_max(mx);
    if (lane == 0) wred[w] = mx;
    __syncthreads();
    if (tid < 64) {
        float s = 0.f;
#pragma unroll
        for (int kk = 0; kk < 16; ++kk) s += s2[kk * 64 + tid];
        deg[b * NN + jg * 128 + tid] = s;
    } else if (tid < 128) {
        int t = tid - 64;
        float s = 0.f;
#pragma unroll
        for (int kk = 0; kk < 16; ++kk) s += s3[kk * 64 + t];
        deg[b * NN + jg * 128 + 64 + t] = s;
    }
    if (tid == 0) {
        float m = wred[0];
#pragma unroll
        for (int i = 1; i < 16; ++i) m = fmaxf(m, wred[i]);
        bmaxp[b * 8 + jg] = m;
    }
}

// kB: pass2, same structure, compact staging. FINAL q0/q1/wj.
__global__ __launch_bounds__(1024, 4) void kB(const float* __restrict__ pts0,
                                              const float* __restrict__ pts1,
                                              const float* __restrict__ deg,
                                              float* __restrict__ q0,
                                              float* __restrict__ q1,
                                              float* __restrict__ wj) {
    __shared__ __align__(16) float l0[NN];
    __shared__ __align__(16) float l1[NN];
    __shared__ __align__(16) float di[NN];
    __shared__ __align__(16) float r0a[NN];
    __shared__ __align__(16) float r1a[NN];
    __shared__ __align__(16) float r2a[NN];
    __shared__ __align__(16) float r0b[NN];
    __shared__ __align__(16) float r1b[NN];
    __shared__ __align__(16) float r2b[NN];
    int blk = blockIdx.x, tid = threadIdx.x, lane = tid & 63, w = tid >> 6;
    int b = blk >> 3, jg = blk & 7;
    l0[tid] = pts0[b * NN + tid];
    l1[tid] = pts1[b * NN + tid];
    di[tid] = 1.0f / sqrtf(deg[b * NN + tid]);
    __syncthreads();
    int jA = jg * 128 + lane, jB = jA + 64;
    float pj0a = l0[jA], pj1a = l1[jA];
    float pj0b = l0[jB], pj1b = l1[jB];
    const float4* v0p = (const float4*)&l0[w * 64];
    const float4* v1p = (const float4*)&l1[w * 64];
    const float4* vdp = (const float4*)&di[w * 64];
    float a0a = 0.f, a1a = 0.f, asa = 0.f;
    float a0b = 0.f, a1b = 0.f, asb = 0.f;
#pragma unroll 4
    for (int g = 0; g < 16; ++g) {
        float4 v0 = v0p[g], v1 = v1p[g], vd = vdp[g];
        float dx, dy, d2, t;
        dx = pj0a - v0.x; dy = pj1a - v1.x; d2 = fmaf(dy, dy, dx * dx);
        t = (d2 <= 0.09f) ? vd.x : 0.0f;
        a0a = fmaf(t, v0.x, a0a); a1a = fmaf(t, v1.x, a1a); asa += t;
        dx = pj0b - v0.x; dy = pj1b - v1.x; d2 = fmaf(dy, dy, dx * dx);
        t = (d2 <= 0.09f) ? vd.x : 0.0f;
        a0b = fmaf(t, v0.x, a0b); a1b = fmaf(t, v1.x, a1b); asb += t;
        dx = pj0a - v0.y; dy = pj1a - v1.y; d2 = fmaf(dy, dy, dx * dx);
        t = (d2 <= 0.09f) ? vd.y : 0.0f;
        a0a = fmaf(t, v0.y, a0a); a1a = fmaf(t, v1.y, a1a); asa += t;
        dx = pj0b - v0.y; dy = pj1b - v1.y; d2 = fmaf(dy, dy, dx * dx);
        t = (d2 <= 0.09f) ? vd.y : 0.0f;
        a0b = fmaf(t, v0.y, a0b); a1b = fmaf(t, v1.y, a1b); asb += t;
        dx = pj0a - v0.z; dy = pj1a - v1.z; d2 = fmaf(dy, dy, dx * dx);
        t = (d2 <= 0.09f) ? vd.z : 0.0f;
        a0a = fmaf(t, v0.z, a0a); a1a = fmaf(t, v1.z, a1a); asa += t;
        dx = pj0b - v0.z; dy = pj1b - v1.z; d2 = fmaf(dy, dy, dx * dx);
        t = (d2 <= 0.09f) ? vd.z : 0.0f;
        a0b = fmaf(t, v0.z, a0b); a1b = fmaf(t, v1.z, a1b); asb += t;
        dx = pj0a - v0.w; dy = pj1a - v1.w; d2 = fmaf(dy, dy, dx * dx);
        t = (d2 <= 0.09f) ? vd.w : 0.0f;
        a0a = fmaf(t, v0.w, a0a); a1a = fmaf(t, v1.w, a1a); asa += t;
        dx = pj0b - v0.w; dy = pj1b - v1.w; d2 = fmaf(dy, dy, dx * dx);
        t = (d2 <= 0.09f) ? vd.w : 0.0f;
        a0b = fmaf(t, v0.w, a0b); a1b = fmaf(t, v1.w, a1b); asb += t;
    }
    r0a[tid] = a0a; r1a[tid] = a1a; r2a[tid] = asa;
    r0b[tid] = a0b; r1b[tid] = a1b; r2b[tid] = asb;
    __syncthreads();
    if (tid < 128) {
        int t = tid & 63;
        const float* R0 = (tid < 64) ? r0a : r0b;
        const float* R1 = (tid < 64) ? r1a : r1b;
        const float* R2 = (tid < 64) ? r2a : r2b;
        int j = jg * 128 + ((tid < 64) ? 0 : 64) + t;
        float s0 = 0.f, s1 = 0.f, ss = 0.f;
#pragma unroll
        for (int kk = 0; kk < 16; ++kk) {
            s0 += R0[kk * 64 + t];
            s1 += R1[kk * 64 + t];
            ss += R2[kk * 64 + t];
        }
        float dj = di[j];
        q0[b * NN + j] = dj * s0;
        q1[b * NN + j] = dj * s1;
        wj[b * NN + j] = dj * ss * (1.0f / NN);
    }
}

// kF: hsum + collapsed epilogue. 32 blocks x 1024.
__global__ __launch_bounds__(1024, 4) void kF(const float* __restrict__ q0,
                                              const float* __restrict__ q1,
                                              const float* __restrict__ wj,
                                              const float* __restrict__ W1,
                                              const float* __restrict__ b1,
                                              const float* __restrict__ Wg,
                                              const float* __restrict__ bg,
                                              const float* __restrict__ Wm1,
                                              const float* __restrict__ bm1,
                                              const float* __restrict__ Wp,
                                              const float* __restrict__ bp,
                                              const float* __restrict__ bm0,
                                              const float* __restrict__ mlp_p,
                                              const float* __restrict__ bmaxp,
                                              const float* __restrict__ spd,
                                              const float* __restrict__ E,
                                              const float* __restrict__ cE,
                                              float* __restrict__ out) {
    __shared__ __align__(16) float sq0[NN];
    __shared__ __align__(16) float sq1[NN];
    __shared__ __align__(16) float sw[NN];
    __shared__ __align__(16) float hpp[4][HID];
    __shared__ __align__(16) float hs[HID];
    __shared__ float sx1[MLPH];
    __shared__ float sxf2[MLPH];
    __shared__ float sglo[8];
    int b = blockIdx.x, tid = threadIdx.x;
    sq0[tid] = q0[b * NN + tid];
    sq1[tid] = q1[b * NN + tid];
    sw[tid]  = wj[b * NN + tid];
    if (tid >= 448 && tid < 512) {   // xf1 = relu(mlp row dot + bm0)
        int h = tid - 448;
        sx1[h] = fmaxf(mlp_p[b * MLPH + h] + bm0[h], 0.f);
    }
    __syncthreads();
    {   // hsum, 4-way j-parallel
        int h = tid & 255, jq = tid >> 8;
        float w10 = W1[h * 2], w11 = W1[h * 2 + 1], bb = b1[h];
        float acc = 0.f;
        const float4* q0v4 = (const float4*)&sq0[jq * 256];
        const float4* q1v4 = (const float4*)&sq1[jq * 256];
        const float4* wv4  = (const float4*)&sw[jq * 256];
#pragma unroll 4
        for (int g = 0; g < 64; ++g) {
            float4 q0v = q0v4[g], q1v = q1v4[g], wv = wv4[g];
            acc = fmaf(wv.x, fmaxf(fmaf(q1v.x, w11, fmaf(q0v.x, w10, bb)), 0.f), acc);
            acc = fmaf(wv.y, fmaxf(fmaf(q1v.y, w11, fmaf(q0v.y, w10, bb)), 0.f), acc);
            acc = fmaf(wv.z, fmaxf(fmaf(q1v.z, w11, fmaf(q0v.z, w10, bb)), 0.f), acc);
            acc = fmaf(wv.w, fmaxf(fmaf(q1v.w, w11, fmaf(q0v.w, w10, bb)), 0.f), acc);
        }
        hpp[jq][h] = acc;
    }
    __syncthreads();
    if (tid < HID) {
        hs[tid] = hpp[0][tid] + hpp[1][tid] + hpp[2][tid] + hpp[3][tid];
    } else if (tid < HID + MLPH) {
        int t = tid - HID;
        float a = bm1[t];
        const float* wv = Wm1 + t * MLPH;
#pragma unroll
        for (int k = 0; k < MLPH; ++k) a = fmaf(wv[k], sx1[k], a);
        sxf2[t] = fmaxf(a, 0.f);
    } else if (tid < HID + MLPH + 8) {
        int t = tid - HID - MLPH;
        float mx = 0.f;
#pragma unroll
        for (int g = 0; g < 8; ++g) mx = fmaxf(mx, bmaxp[b * 8 + g]);
        float avg  = spd[b] * (1.0f / NN);
        float dens = 1.0f / sqrtf(mx);
        sglo[t] = fmaxf(fmaf(Wg[t * 2], avg, fmaf(Wg[t * 2 + 1], dens, bg[t])), 0.f);
    }
    __syncthreads();
    if (tid < 512) {
        int o = tid >> 6, lane = tid & 63;
        const float* Eo = E + o * HID;
        float a = Eo[lane] * hs[lane];
        a = fmaf(Eo[lane + 64],  hs[lane + 64],  a);
        a = fmaf(Eo[lane + 128], hs[lane + 128], a);
        a = fmaf(Eo[lane + 192], hs[lane + 192], a);
        a = fmaf(Wp[o * CATN + lane], sxf2[lane], a);
        a = wave_sum(a);
        if (lane == 0) {
            const float* wg = Wp + o * CATN + MLPH + HID;
#pragma unroll
            for (int g = 0; g < 8; ++g) a = fmaf(wg[g], sglo[g], a);
            out[b * OUTN + o] = a + cE[o] + bp[o];
        }
    }
}

extern "C" void kernel_launch(void* const* d_in, const int* in_sizes, int n_in,
                              void* d_out, int out_size, void* d_ws, size_t ws_size,
                              hipStream_t stream) {
    const float* x   = (const float*)d_in[0];
    const float* W1  = (const float*)d_in[1];
    const float* b1  = (const float*)d_in[2];
    const float* W2  = (const float*)d_in[3];
    const float* b2  = (const float*)d_in[4];
    const float* Wfc = (const float*)d_in[5];
    const float* bfc = (const float*)d_in[6];
    const float* Wg  = (const float*)d_in[7];
    const float* bg  = (const float*)d_in[8];
    const float* Wm0 = (const float*)d_in[9];
    const float* bm0 = (const float*)d_in[10];
    const float* Wm1 = (const float*)d_in[11];
    const float* bm1 = (const float*)d_in[12];
    const float* Wp  = (const float*)d_in[13];
    const float* bp  = (const float*)d_in[14];
    float* out = (float*)d_out;
    float* ws  = (float*)d_ws;

    float* pts0  = ws;            // 32768
    float* pts1  = ws + 32768;    // 32768
    float* deg   = ws + 65536;    // 32768
    float* q0    = ws + 98304;    // 32768
    float* q1    = ws + 131072;   // 32768
    float* wj    = ws + 163840;   // 32768
    float* mlp_p = ws + 196608;   // 2048
    float* bmaxp = ws + 198656;   // 256
    float* spd   = ws + 198912;   // 32
    float* E     = ws + 198944;   // 2048
    float* cE    = ws + 200992;   // 8
    // every ws cell is written before it is read -> no zero-init needed.

    kPM<<<104, 1024, 0, stream>>>(x, Wm0, W2, b2, Wfc, bfc, Wp,
                                  pts0, pts1, spd, mlp_p, E, cE);
    kA<<<256,  1024, 0, stream>>>(pts0, pts1, deg, bmaxp);
    kB<<<256,  1024, 0, stream>>>(pts0, pts1, deg, q0, q1, wj);
    kF<<<BB,   1024, 0, stream>>>(q0, q1, wj, W1, b1, Wg, bg, Wm1, bm1, Wp, bp,
                                  bm0, mlp_p, bmaxp, spd, E, cE, out);
}